// Round 5
// baseline (333.216 us; speedup 1.0000x reference)
//
#include <hip/hip_runtime.h>
#include <stdint.h>

#define D_MODEL 1024
#define NH 16
#define DK 64
#define BATCH 2
#define SEQ 2048
#define MROWS (BATCH*SEQ)   // 4096

typedef float f32x4 __attribute__((ext_vector_type(4)));
typedef __bf16 bf16x8 __attribute__((ext_vector_type(8)));

#define AS1 __attribute__((address_space(1)))
#define AS3 __attribute__((address_space(3)))

#if __has_builtin(__builtin_amdgcn_exp2f)
#define EXP2F(x) __builtin_amdgcn_exp2f(x)
#else
#define EXP2F(x) exp2f(x)
#endif
#if __has_builtin(__builtin_amdgcn_rcpf)
#define RCPF(x) __builtin_amdgcn_rcpf(x)
#else
#define RCPF(x) (1.0f/(x))
#endif

// async global->LDS, 16B per lane, dest = wave-uniform base + lane*16
static __device__ __forceinline__ void gld_lds16(const void* g, void* l) {
    __builtin_amdgcn_global_load_lds((const AS1 unsigned int*)g,
                                     (AS3 unsigned int*)l, 16, 0, 0);
}

// HW f32->bf16 (RNE); compiler pairs adjacent casts into v_cvt_pk_bf16_f32
static __device__ __forceinline__ unsigned short bfbits(float f) {
    return __builtin_bit_cast(unsigned short, (__bf16)f);
}
static __device__ __forceinline__ unsigned int pk2bf(float a, float b) {
    return (unsigned int)bfbits(a) | ((unsigned int)bfbits(b) << 16);
}
static __device__ __forceinline__ float bf2f(unsigned int u) {
    return __builtin_bit_cast(float, u << 16);
}

// ---------------------------------------------------------------- prep ----
struct PrepArgs {
    const float* src[7];
    unsigned short* dst[7];
    int n4[7];
};

__global__ __launch_bounds__(256) void prep_cvt(PrepArgs a) {
    const int z = blockIdx.y;
    const float4* s = (const float4*)a.src[z];
    uint2* d = (uint2*)a.dst[z];
    const int n = a.n4[z];
    for (int i = blockIdx.x * blockDim.x + threadIdx.x; i < n;
         i += gridDim.x * blockDim.x) {
        float4 v = s[i];
        uint2 o;
        o.x = pk2bf(v.x, v.y);
        o.y = pk2bf(v.z, v.w);
        d[i] = o;
    }
}

// ---------------------------------------------------------------- GEMM ----
// C[m,n] = (sum_k A[m,k]*W[n,k] + bias[n]) * scale
// A: MxK bf16 row-major, W: NxK bf16 row-major, K=1024. BMxBN tile, BK=64,
// 4 waves (2x2), global_load_lds + source-side XOR swizzle.
// hm: 0 = flat [row][1024]; 1 = head-major [bh][s][64]; 2 = V-transposed
// [bh][d][s] (vectorized ushort4 along s).
struct GemmArgs {
    const unsigned short* A[3];
    const unsigned short* W[3];
    const float* bias[3];
    void* C[3];
    float scale[3];
    int hm[3];
};

template<bool OUT_F32, int BM, int BN>
__global__ __launch_bounds__(256) void gemm_bt(GemmArgs g) {
    constexpr int IM = BM / 32;          // 16-row frags per wave
    constexpr int JN = BN / 32;          // 16-col frags per wave
    __shared__ unsigned short As[BM * 64];
    __shared__ unsigned short Bs[BN * 64];
    const int z = blockIdx.z;
    const char* A = (const char*)g.A[z];
    const char* W = (const char*)g.W[z];
    const float* bias = g.bias[z];
    const float scale = g.scale[z];
    const int hm = g.hm[z];
    const int t = threadIdx.x;
    const int w = t >> 6, lane = t & 63;
    const int m0 = blockIdx.x * BM, n0 = blockIdx.y * BN;
    const int wm = (w >> 1) * (BM / 2), wn = (w & 1) * (BN / 2);

    const int srow = t >> 3;
    const int csw = ((t & 7) * 16) ^ ((srow & 7) << 4);
    const char* pA = A + (size_t)(m0 + srow) * 2048 + csw;
    const char* pW = W + (size_t)(n0 + srow) * 2048 + csw;

    f32x4 acc[IM][JN];
#pragma unroll
    for (int i = 0; i < IM; ++i)
#pragma unroll
        for (int j = 0; j < JN; ++j)
            acc[i][j] = (f32x4){0.f, 0.f, 0.f, 0.f};

    const int g4 = lane >> 4;
    const int kg16 = g4 * 16;
    const int swl = (lane & 7) << 4;

    for (int kt = 0; kt < 16; ++kt) {
        __syncthreads();
#pragma unroll
        for (int p = 0; p < IM; ++p)
            gld_lds16(pA + (size_t)p * (32 * 2048), &As[w * 512 + p * 2048]);
#pragma unroll
        for (int p = 0; p < JN; ++p)
            gld_lds16(pW + (size_t)p * (32 * 2048), &Bs[w * 512 + p * 2048]);
        pA += 128; pW += 128;
        __syncthreads();
#pragma unroll
        for (int ks = 0; ks < 2; ++ks) {
            bf16x8 af[IM], bfv[JN];
#pragma unroll
            for (int i = 0; i < IM; ++i) {
                int ra = wm + i * 16 + (lane & 15);
                af[i] = *(const bf16x8*)((const char*)As + ra * 128 +
                                         ((ks * 64 + kg16) ^ swl));
            }
#pragma unroll
            for (int j = 0; j < JN; ++j) {
                int rb = wn + j * 16 + (lane & 15);
                bfv[j] = *(const bf16x8*)((const char*)Bs + rb * 128 +
                                          ((ks * 64 + kg16) ^ swl));
            }
            __builtin_amdgcn_s_setprio(1);
#pragma unroll
            for (int i = 0; i < IM; ++i)
#pragma unroll
                for (int j = 0; j < JN; ++j)
                    acc[i][j] = __builtin_amdgcn_mfma_f32_16x16x32_bf16(
                        af[i], bfv[j], acc[i][j], 0, 0, 0);
            __builtin_amdgcn_s_setprio(0);
        }
    }

    float bj[JN];
#pragma unroll
    for (int j = 0; j < JN; ++j) bj[j] = bias[n0 + wn + j * 16 + (lane & 15)];

    if (hm == 2) {
        // V-transpose epilogue: [bh][d][s], 4 s-rows per lane -> ushort4
#pragma unroll
        for (int i = 0; i < IM; ++i) {
            int row0 = m0 + wm + i * 16 + (g4 << 2);
            int bb = row0 >> 11, ss0 = row0 & 2047;
#pragma unroll
            for (int j = 0; j < JN; ++j) {
                int col = n0 + wn + j * 16 + (lane & 15);
                int hh = col >> 6, dd = col & 63;
                ushort4 o;
                o.x = bfbits(acc[i][j][0] + bj[j]);
                o.y = bfbits(acc[i][j][1] + bj[j]);
                o.z = bfbits(acc[i][j][2] + bj[j]);
                o.w = bfbits(acc[i][j][3] + bj[j]);
                *(ushort4*)((unsigned short*)g.C[z] +
                            (((size_t)(bb * 16 + hh) * 64 + dd) * 2048 + ss0)) = o;
            }
        }
        return;
    }

#pragma unroll
    for (int i = 0; i < IM; ++i)
#pragma unroll
        for (int r = 0; r < 4; ++r) {
            int row = m0 + wm + i * 16 + g4 * 4 + r;
#pragma unroll
            for (int j = 0; j < JN; ++j) {
                int col = n0 + wn + j * 16 + (lane & 15);
                float v = (acc[i][j][r] + bj[j]) * scale;
                if (OUT_F32) {
                    ((float*)g.C[z])[(size_t)row * 1024 + col] = v;
                } else if (hm) {
                    int bb = row >> 11, ss = row & 2047;
                    int hh = col >> 6, dd = col & 63;
                    ((unsigned short*)g.C[z])
                        [(((size_t)(bb * 16 + hh) * 2048) + ss) * 64 + dd] =
                        bfbits(v);
                } else {
                    ((unsigned short*)g.C[z])[(size_t)row * 1024 + col] =
                        bfbits(v);
                }
            }
        }
}

// ----------------------------------------------------------- attention ----
// KV-split-2 flash attention, NO K/V LDS staging (K,V are L2-resident per
// XCD: all 32 blocks of a bh map to XCD (bh/4)%8, working set ~3 MB < 4 MB).
// K/V fragments load straight from global; only P bounces through per-wave
// swizzled LDS (C->A layout transpose). Zero __syncthreads in main loop.
// Qh/Kh: [bh][s][64] bf16 (Q pre-scaled by log2(e)/8). VtT: [bh][d][s] bf16.
// Emits UNNORMALIZED O (bf16) + per-row (m, l).
__global__ __launch_bounds__(256, 4) void attn_fwd(
    const unsigned short* __restrict__ Qh,
    const unsigned short* __restrict__ Kh,
    const unsigned short* __restrict__ VtT,
    const int* __restrict__ mask,
    unsigned short* __restrict__ Opart,
    float* __restrict__ Mlf,
    float* __restrict__ Llf) {
    __shared__ unsigned short Plds[4][2048];

    // T1: XCD-aware swizzle (nwg=1024, 128 consecutive per XCD)
    const int wg = blockIdx.x + (int)gridDim.x *
                   (blockIdx.y + (int)gridDim.y * blockIdx.z);
    const int swz = (wg & 7) * 128 + (wg >> 3);
    const int sp = swz & 1, qt = (swz >> 1) & 15, bh = swz >> 5;
    const int b = bh >> 4, h = bh & 15;
    const int kvb = sp * 1024;

    const int t = threadIdx.x, w = t >> 6, lane = t & 63;
    const int wq0 = w * 32;
    const int g = lane >> 4;
    const int kg16 = g * 16;
    const int swl = (lane & 7) << 4;

    // per-wave mask-clean check over this split's 1024 keys (no barrier)
    const int* mbase = mask + b * SEQ;
    int myclean = 1;
#pragma unroll
    for (int i = 0; i < 4; ++i) {
        int4 m4 = ((const int4*)(mbase + kvb))[lane + 64 * i];
        myclean &= (m4.x != 0) & (m4.y != 0) & (m4.z != 0) & (m4.w != 0);
    }
    const int clean = (int)__all(myclean);

    // hoist Q fragments (head-major: row stride 128B)
    const char* Qbase = (const char*)Qh + (size_t)bh * (2048 * 128);
    bf16x8 qf[2][2];
#pragma unroll
    for (int nf = 0; nf < 2; ++nf)
#pragma unroll
        for (int ks = 0; ks < 2; ++ks) {
            int row = qt * 128 + wq0 + nf * 16 + (lane & 15);
            qf[nf][ks] = *(const bf16x8*)(Qbase + (size_t)row * 128 +
                                          ks * 64 + kg16);
        }

    bf16x8 onesf;
#pragma unroll
    for (int j = 0; j < 8; ++j) onesf[j] = (__bf16)1.0f;

    f32x4 cacc[2][4], lacc[2];
#pragma unroll
    for (int i = 0; i < 2; ++i) {
        lacc[i] = (f32x4){0.f, 0.f, 0.f, 0.f};
#pragma unroll
        for (int j = 0; j < 4; ++j) cacc[i][j] = (f32x4){0.f, 0.f, 0.f, 0.f};
    }
    float mstate[2] = {-3e38f, -3e38f};

    const char* Kbyte = (const char*)Kh + (size_t)bh * (2048 * 128);
    const char* Vbyte = (const char*)VtT + (size_t)bh * (64 * 4096);

    unsigned short* Pw = &Plds[w][0];

#pragma unroll 2
    for (int it = 0; it < 16; ++it) {
        const int kv0 = kvb + it * 64;

        // --- S^T = K . Q^T (K fragments direct from global, coalesced) ---
        f32x4 sacc[4][2];
#pragma unroll
        for (int i = 0; i < 4; ++i)
#pragma unroll
            for (int j = 0; j < 2; ++j) sacc[i][j] = (f32x4){0.f, 0.f, 0.f, 0.f};
#pragma unroll
        for (int ks = 0; ks < 2; ++ks) {
            bf16x8 kf[4];
#pragma unroll
            for (int mf = 0; mf < 4; ++mf)
                kf[mf] = *(const bf16x8*)(Kbyte +
                    (size_t)(kv0 + mf * 16 + (lane & 15)) * 128 +
                    ks * 64 + kg16);
            __builtin_amdgcn_s_setprio(1);
#pragma unroll
            for (int mf = 0; mf < 4; ++mf)
#pragma unroll
                for (int nf = 0; nf < 2; ++nf)
                    sacc[mf][nf] = __builtin_amdgcn_mfma_f32_16x16x32_bf16(
                        kf[mf], qf[nf][ks], sacc[mf][nf], 0, 0, 0);
            __builtin_amdgcn_s_setprio(0);
        }

        if (!clean) {
#pragma unroll
            for (int mf = 0; mf < 4; ++mf) {
                int4 mk = *(const int4*)(mbase + kv0 + mf * 16 + g * 4);
#pragma unroll
                for (int r = 0; r < 4; ++r) {
                    if ((&mk.x)[r] == 0) {
                        sacc[mf][0][r] = -1e9f;
                        sacc[mf][1][r] = -1e9f;
                    }
                }
            }
        }

        // per-q max (tree + 2 cross-group shuffles); defer-max rescale
        float vm[2];
#pragma unroll
        for (int nf = 0; nf < 2; ++nf) {
            float a0 = fmaxf(fmaxf(sacc[0][nf][0], sacc[0][nf][1]),
                             fmaxf(sacc[0][nf][2], sacc[0][nf][3]));
            float a1 = fmaxf(fmaxf(sacc[1][nf][0], sacc[1][nf][1]),
                             fmaxf(sacc[1][nf][2], sacc[1][nf][3]));
            float a2 = fmaxf(fmaxf(sacc[2][nf][0], sacc[2][nf][1]),
                             fmaxf(sacc[2][nf][2], sacc[2][nf][3]));
            float a3 = fmaxf(fmaxf(sacc[3][nf][0], sacc[3][nf][1]),
                             fmaxf(sacc[3][nf][2], sacc[3][nf][3]));
            float m4x = fmaxf(fmaxf(a0, a1), fmaxf(a2, a3));
            m4x = fmaxf(m4x, __shfl_xor(m4x, 16));
            vm[nf] = fmaxf(m4x, __shfl_xor(m4x, 32));
        }
        if (!__all((vm[0] <= mstate[0] + 8.f) & (vm[1] <= mstate[1] + 8.f))) {
            float sc[2];
#pragma unroll
            for (int nf = 0; nf < 2; ++nf) {
                float mnew = fmaxf(mstate[nf], vm[nf]);
                sc[nf] = EXP2F(mstate[nf] - mnew);
                mstate[nf] = mnew;
            }
#pragma unroll
            for (int mq = 0; mq < 2; ++mq)
#pragma unroll
                for (int r = 0; r < 4; ++r) {
                    float scb = __shfl(sc[mq], g * 4 + r);
                    lacc[mq][r] *= scb;
#pragma unroll
                    for (int nd = 0; nd < 4; ++nd) cacc[mq][nd][r] *= scb;
                }
        }

        // P = 2^(S'-m), pack bf16, write to per-wave LDS (b64, swizzled)
#pragma unroll
        for (int nf = 0; nf < 2; ++nf) {
            float mn = mstate[nf];
#pragma unroll
            for (int mf = 0; mf < 4; ++mf) {
                unsigned int d0 = pk2bf(EXP2F(sacc[mf][nf][0] - mn),
                                        EXP2F(sacc[mf][nf][1] - mn));
                unsigned int d1 = pk2bf(EXP2F(sacc[mf][nf][2] - mn),
                                        EXP2F(sacc[mf][nf][3] - mn));
                int q = nf * 16 + (lane & 15);
                int kb = mf * 32 + g * 8;
                unsigned long long pv =
                    (unsigned long long)d0 | ((unsigned long long)d1 << 32);
                *(unsigned long long*)((char*)Pw + q * 128 +
                                       (kb ^ ((q & 7) << 4))) = pv;
            }
        }

        // --- PV + l accumulation (V^T fragments direct from global) ---
#pragma unroll
        for (int ks = 0; ks < 2; ++ks) {
            bf16x8 pa[2], vf[4];
#pragma unroll
            for (int mq = 0; mq < 2; ++mq) {
                int r = mq * 16 + (lane & 15);
                pa[mq] = *(const bf16x8*)((const char*)Pw + r * 128 +
                                          ((ks * 64 + kg16) ^ swl));
            }
#pragma unroll
            for (int nd = 0; nd < 4; ++nd)
                vf[nd] = *(const bf16x8*)(Vbyte +
                    (size_t)(nd * 16 + (lane & 15)) * 4096 +
                    (size_t)(kv0 + ks * 32 + g * 8) * 2);
            __builtin_amdgcn_s_setprio(1);
#pragma unroll
            for (int mq = 0; mq < 2; ++mq) {
                lacc[mq] = __builtin_amdgcn_mfma_f32_16x16x32_bf16(
                    pa[mq], onesf, lacc[mq], 0, 0, 0);
#pragma unroll
                for (int nd = 0; nd < 4; ++nd)
                    cacc[mq][nd] = __builtin_amdgcn_mfma_f32_16x16x32_bf16(
                        pa[mq], vf[nd], cacc[mq][nd], 0, 0, 0);
            }
            __builtin_amdgcn_s_setprio(0);
        }
    }

    // emit unnormalized O (bf16) + per-row m, l
#pragma unroll
    for (int mq = 0; mq < 2; ++mq)
#pragma unroll
        for (int r = 0; r < 4; ++r) {
            int sq = qt * 128 + wq0 + mq * 16 + g * 4 + r;
            size_t row = (size_t)(sp * 4096 + b * 2048 + sq);
#pragma unroll
            for (int nd = 0; nd < 4; ++nd) {
                int col = h * 64 + nd * 16 + (lane & 15);
                Opart[row * 1024 + col] = bfbits(cacc[mq][nd][r]);
            }
        }
    if ((lane & 15) == 0) {
#pragma unroll
        for (int mq = 0; mq < 2; ++mq)
#pragma unroll
            for (int r = 0; r < 4; ++r)
                Llf[sp * 65536 + bh * 2048 + qt * 128 + wq0 + mq * 16 +
                    g * 4 + r] = lacc[mq][r];
    }
    if (g == 0) {
#pragma unroll
        for (int mq = 0; mq < 2; ++mq)
            Mlf[sp * 65536 + bh * 2048 + qt * 128 + wq0 + mq * 16 +
                (lane & 15)] = mstate[mq];
    }
}

// ------------------------------------------------------------ combine ----
// Cx[row][col] = (O1*w1 + O2*w2) / (l1*w1 + l2*w2), w_i = 2^(m_i - max)
__global__ __launch_bounds__(256) void attn_combine(
    const unsigned short* __restrict__ Op,
    const float* __restrict__ Mlf,
    const float* __restrict__ Llf,
    unsigned short* __restrict__ Cx) {
    const int idx = blockIdx.x * 256 + threadIdx.x;   // 524288
    const int row = idx >> 7;
    const int c8 = (idx & 127) << 3;
    const int b = row >> 11, s = row & 2047, h = c8 >> 6;
    const int li = (b * 16 + h) * 2048 + s;
    const float m1 = Mlf[li], m2 = Mlf[65536 + li];
    const float l1 = Llf[li], l2 = Llf[65536 + li];
    const float mx = fmaxf(m1, m2);
    float w1 = EXP2F(m1 - mx), w2 = EXP2F(m2 - mx);
    const float inv = RCPF(fmaf(l1, w1, l2 * w2));
    w1 *= inv; w2 *= inv;
    const uint4 o1 = *(const uint4*)(Op + (size_t)row * 1024 + c8);
    const uint4 o2 = *(const uint4*)(Op + (size_t)(4096 + row) * 1024 + c8);
    uint4 o;
    unsigned int rr[4];
#pragma unroll
    for (int j = 0; j < 4; ++j) {
        unsigned int a = ((const unsigned int*)&o1)[j];
        unsigned int c = ((const unsigned int*)&o2)[j];
        float x0 = bf2f(a & 0xffffu) * w1 + bf2f(c & 0xffffu) * w2;
        float x1 = bf2f(a >> 16) * w1 + bf2f(c >> 16) * w2;
        rr[j] = pk2bf(x0, x1);
    }
    o.x = rr[0]; o.y = rr[1]; o.z = rr[2]; o.w = rr[3];
    *(uint4*)(Cx + (size_t)row * 1024 + c8) = o;
}

// -------------------------------------------------------------- launch ----
extern "C" void kernel_launch(void* const* d_in, const int* in_sizes, int n_in,
                              void* d_out, int out_size, void* d_ws, size_t ws_size,
                              hipStream_t stream) {
    const float* q   = (const float*)d_in[0];
    const float* k   = (const float*)d_in[1];
    const float* v   = (const float*)d_in[2];
    const int* mask  = (const int*)d_in[3];
    const float* Wq  = (const float*)d_in[4];
    const float* bq  = (const float*)d_in[5];
    const float* Wk  = (const float*)d_in[6];
    const float* bk  = (const float*)d_in[7];
    const float* Wv  = (const float*)d_in[8];
    const float* bv  = (const float*)d_in[9];
    const float* Wo  = (const float*)d_in[10];
    const float* bo  = (const float*)d_in[11];

    unsigned short* ws = (unsigned short*)d_ws;
    const size_t NX = (size_t)MROWS * D_MODEL;   // 4194304 elems
    const size_t NW = (size_t)D_MODEL * D_MODEL; // 1048576 elems
    unsigned short* Xq  = ws;              // reused: Opart (2 splits, 16 MB)
    unsigned short* Xk  = Xq + NX;
    unsigned short* Xv  = Xk + NX;         // reused: Mlf/Llf (1 MB)
    unsigned short* Wqb = Xv + NX;
    unsigned short* Wkb = Wqb + NW;
    unsigned short* Wvb = Wkb + NW;
    unsigned short* Wob = Wvb + NW;
    unsigned short* Qhd = Wob + NW;
    unsigned short* Khd = Qhd + NX;
    unsigned short* Vtt = Khd + NX;
    unsigned short* Cx  = Vtt + NX;

    PrepArgs pa;
    pa.src[0] = q;  pa.src[1] = k;  pa.src[2] = v;
    pa.src[3] = Wq; pa.src[4] = Wk; pa.src[5] = Wv; pa.src[6] = Wo;
    pa.dst[0] = Xq;  pa.dst[1] = Xk;  pa.dst[2] = Xv;
    pa.dst[3] = Wqb; pa.dst[4] = Wkb; pa.dst[5] = Wvb; pa.dst[6] = Wob;
    for (int i = 0; i < 3; ++i) pa.n4[i] = (int)(NX / 4);
    for (int i = 3; i < 7; ++i) pa.n4[i] = (int)(NW / 4);
    prep_cvt<<<dim3(256, 7), dim3(256), 0, stream>>>(pa);

    GemmArgs gq;
    gq.A[0] = Xq;  gq.A[1] = Xk;  gq.A[2] = Xv;
    gq.W[0] = Wqb; gq.W[1] = Wkb; gq.W[2] = Wvb;
    gq.bias[0] = bq; gq.bias[1] = bk; gq.bias[2] = bv;
    gq.C[0] = Qhd; gq.C[1] = Khd; gq.C[2] = Vtt;
    // Q pre-scale: (1/sqrt(64)) * log2(e)  -> softmax runs in exp2 domain
    gq.scale[0] = 0.125f * 1.44269504088896340736f;
    gq.scale[1] = 1.f; gq.scale[2] = 1.f;
    gq.hm[0] = 1; gq.hm[1] = 1; gq.hm[2] = 2;
    gemm_bt<false, 128, 128><<<dim3(32, 8, 3), dim3(256), 0, stream>>>(gq);

    // Opart reuses Xq/Xk (16 MB); Mlf/Llf reuse Xv (1 MB)
    unsigned short* Opart = Xq;
    float* Mlf = (float*)Xv;
    float* Llf = Mlf + 2 * 65536;
    attn_fwd<<<dim3(16, 32, 2), dim3(256), 0, stream>>>(
        Qhd, Khd, Vtt, mask, Opart, Mlf, Llf);

    attn_combine<<<dim3(2048), dim3(256), 0, stream>>>(Opart, Mlf, Llf, Cx);

    GemmArgs go;
    go.A[0] = Cx; go.W[0] = Wob; go.bias[0] = bo; go.C[0] = d_out;
    go.scale[0] = 1.f; go.hm[0] = 0;
    go.A[1] = go.A[2] = nullptr; go.W[1] = go.W[2] = nullptr;
    go.bias[1] = go.bias[2] = nullptr; go.C[1] = go.C[2] = nullptr;
    go.scale[1] = go.scale[2] = 1.f; go.hm[1] = go.hm[2] = 0;
    gemm_bt<true, 128, 64><<<dim3(32, 16, 1), dim3(256), 0, stream>>>(go);
}

// Round 6
// 244.238 us; speedup vs baseline: 1.3643x; 1.3643x over previous
//
#include <hip/hip_runtime.h>
#include <stdint.h>

#define D_MODEL 1024
#define NH 16
#define DK 64
#define BATCH 2
#define SEQ 2048
#define MROWS (BATCH*SEQ)   // 4096

typedef float f32x4 __attribute__((ext_vector_type(4)));
typedef __bf16 bf16x8 __attribute__((ext_vector_type(8)));

#define AS1 __attribute__((address_space(1)))
#define AS3 __attribute__((address_space(3)))

#if __has_builtin(__builtin_amdgcn_exp2f)
#define EXP2F(x) __builtin_amdgcn_exp2f(x)
#else
#define EXP2F(x) exp2f(x)
#endif
#if __has_builtin(__builtin_amdgcn_rcpf)
#define RCPF(x) __builtin_amdgcn_rcpf(x)
#else
#define RCPF(x) (1.0f/(x))
#endif

// async global->LDS, 16B per lane, dest = wave-uniform base + lane*16
static __device__ __forceinline__ void gld_lds16(const void* g, void* l) {
    __builtin_amdgcn_global_load_lds((const AS1 unsigned int*)g,
                                     (AS3 unsigned int*)l, 16, 0, 0);
}

// HW f32->bf16 (RNE); compiler pairs adjacent casts into v_cvt_pk_bf16_f32
static __device__ __forceinline__ unsigned short bfbits(float f) {
    return __builtin_bit_cast(unsigned short, (__bf16)f);
}
static __device__ __forceinline__ unsigned int pk2bf(float a, float b) {
    return (unsigned int)bfbits(a) | ((unsigned int)bfbits(b) << 16);
}

// ---------------------------------------------------------------- prep ----
struct PrepArgs {
    const float* src[7];
    unsigned short* dst[7];
    int n4[7];
};

__global__ __launch_bounds__(256) void prep_cvt(PrepArgs a) {
    const int z = blockIdx.y;
    const float4* s = (const float4*)a.src[z];
    uint2* d = (uint2*)a.dst[z];
    const int n = a.n4[z];
    for (int i = blockIdx.x * blockDim.x + threadIdx.x; i < n;
         i += gridDim.x * blockDim.x) {
        float4 v = s[i];
        uint2 o;
        o.x = pk2bf(v.x, v.y);
        o.y = pk2bf(v.z, v.w);
        d[i] = o;
    }
}

// ---------------------------------------------------------------- GEMM ----
struct GemmArgs {
    const unsigned short* A[3];
    const unsigned short* W[3];
    const float* bias[3];
    void* C[3];
    float scale[3];
    int hm[3];
};

// ---- classic 128xBN m97-style (used for out-proj) ------------------------
template<bool OUT_F32, int BM, int BN>
__global__ __launch_bounds__(256) void gemm_bt(GemmArgs g) {
    constexpr int IM = BM / 32;
    constexpr int JN = BN / 32;
    __shared__ unsigned short As[BM * 64];
    __shared__ unsigned short Bs[BN * 64];
    const int z = blockIdx.z;
    const char* A = (const char*)g.A[z];
    const char* W = (const char*)g.W[z];
    const float* bias = g.bias[z];
    const float scale = g.scale[z];
    const int hm = g.hm[z];
    const int t = threadIdx.x;
    const int w = t >> 6, lane = t & 63;
    const int m0 = blockIdx.x * BM, n0 = blockIdx.y * BN;
    const int wm = (w >> 1) * (BM / 2), wn = (w & 1) * (BN / 2);

    const int srow = t >> 3;
    const int csw = ((t & 7) * 16) ^ ((srow & 7) << 4);
    const char* pA = A + (size_t)(m0 + srow) * 2048 + csw;
    const char* pW = W + (size_t)(n0 + srow) * 2048 + csw;

    f32x4 acc[IM][JN];
#pragma unroll
    for (int i = 0; i < IM; ++i)
#pragma unroll
        for (int j = 0; j < JN; ++j)
            acc[i][j] = (f32x4){0.f, 0.f, 0.f, 0.f};

    const int g4 = lane >> 4;
    const int kg16 = g4 * 16;
    const int swl = (lane & 7) << 4;

    for (int kt = 0; kt < 16; ++kt) {
        __syncthreads();
#pragma unroll
        for (int p = 0; p < IM; ++p)
            gld_lds16(pA + (size_t)p * (32 * 2048), &As[w * 512 + p * 2048]);
#pragma unroll
        for (int p = 0; p < JN; ++p)
            gld_lds16(pW + (size_t)p * (32 * 2048), &Bs[w * 512 + p * 2048]);
        pA += 128; pW += 128;
        __syncthreads();
#pragma unroll
        for (int ks = 0; ks < 2; ++ks) {
            bf16x8 af[IM], bfv[JN];
#pragma unroll
            for (int i = 0; i < IM; ++i) {
                int ra = wm + i * 16 + (lane & 15);
                af[i] = *(const bf16x8*)((const char*)As + ra * 128 +
                                         ((ks * 64 + kg16) ^ swl));
            }
#pragma unroll
            for (int j = 0; j < JN; ++j) {
                int rb = wn + j * 16 + (lane & 15);
                bfv[j] = *(const bf16x8*)((const char*)Bs + rb * 128 +
                                          ((ks * 64 + kg16) ^ swl));
            }
            __builtin_amdgcn_s_setprio(1);
#pragma unroll
            for (int i = 0; i < IM; ++i)
#pragma unroll
                for (int j = 0; j < JN; ++j)
                    acc[i][j] = __builtin_amdgcn_mfma_f32_16x16x32_bf16(
                        af[i], bfv[j], acc[i][j], 0, 0, 0);
            __builtin_amdgcn_s_setprio(0);
        }
    }

    float bj[JN];
#pragma unroll
    for (int j = 0; j < JN; ++j) bj[j] = bias[n0 + wn + j * 16 + (lane & 15)];

#pragma unroll
    for (int i = 0; i < IM; ++i)
#pragma unroll
        for (int r = 0; r < 4; ++r) {
            int row = m0 + wm + i * 16 + g4 * 4 + r;
#pragma unroll
            for (int j = 0; j < JN; ++j) {
                int col = n0 + wn + j * 16 + (lane & 15);
                float v = (acc[i][j][r] + bj[j]) * scale;
                if (OUT_F32) {
                    ((float*)g.C[z])[(size_t)row * 1024 + col] = v;
                } else if (hm) {
                    int bb = row >> 11, ss = row & 2047;
                    int hh = col >> 6, dd = col & 63;
                    ((unsigned short*)g.C[z])
                        [(((size_t)(bb * 16 + hh) * 2048) + ss) * 64 + dd] =
                        bfbits(v);
                } else {
                    ((unsigned short*)g.C[z])[(size_t)row * 1024 + col] =
                        bfbits(v);
                }
            }
        }
}

// ---- 256x256 8-phase (T2+T3+T4+T5) for the QKV projections ---------------
// 512 thr / 8 waves (2M x 4N, wave tile 128x64), BK=64, LDS 128KB dbuf.
// Tile t reads buf[t&1]; t's 4 phases stage tile t+1 into buf[~t&1]
// (one half-tile per phase). Counted vmcnt(2)+barrier at tile boundary
// ONLY (never vmcnt(0) mid-loop). Raw s_barrier (no implicit vmcnt drain).
__global__ __launch_bounds__(512, 2) void gemm_8p(GemmArgs g) {
    __shared__ unsigned short Al[2][256 * 64];   // 64 KB
    __shared__ unsigned short Bl[2][256 * 64];   // 64 KB
    const int z = blockIdx.z;
    const char* A = (const char*)g.A[z];
    const char* W = (const char*)g.W[z];
    const float* bias = g.bias[z];
    const float scale = g.scale[z];
    const int hm = g.hm[z];
    const int t = threadIdx.x;
    const int w = t >> 6, lane = t & 63;
    const int m0 = blockIdx.x * 256, n0 = blockIdx.y * 256;
    const int wm = (w >> 2) * 128, wn = (w & 3) * 64;
    const int g4 = lane >> 4, kg16 = g4 * 16, swl = (lane & 7) << 4;

    // staging: thread covers rows (t>>3)+{0,64} of a 128-row half, 16B chunk
    // (t&7), source col pre-swizzled (XOR involution matches frag reads)
    const int csw = ((t & 7) * 16) ^ (((t >> 3) & 7) << 4);
    const char* pA = A + (size_t)(m0 + (t >> 3)) * 2048 + csw;
    const char* pW = W + (size_t)(n0 + (t >> 3)) * 2048 + csw;

    auto stA = [&](int kt, int buf, int half) {
        const char* s = pA + (size_t)half * (128 * 2048) + kt * 128;
        unsigned short* d = &Al[buf][(half * 128 + w * 8) * 64];
        gld_lds16(s, d);
        gld_lds16(s + (size_t)64 * 2048, d + 64 * 64);
    };
    auto stB = [&](int kt, int buf, int half) {
        const char* s = pW + (size_t)half * (128 * 2048) + kt * 128;
        unsigned short* d = &Bl[buf][(half * 128 + w * 8) * 64];
        gld_lds16(s, d);
        gld_lds16(s + (size_t)64 * 2048, d + 64 * 64);
    };

    f32x4 acc[8][4];
#pragma unroll
    for (int i = 0; i < 8; ++i)
#pragma unroll
        for (int j = 0; j < 4; ++j) acc[i][j] = (f32x4){0.f, 0.f, 0.f, 0.f};

    bf16x8 afq[4][2], bq0[2][2], bq1[2][2];

    // prologue: tile 0, all 4 halves (8 loads/wave in flight)
    stA(0, 0, 0); stA(0, 0, 1); stB(0, 0, 0); stB(0, 0, 1);

    for (int kt = 0; kt < 16; ++kt) {
        const int bc = kt & 1, bn2 = bc ^ 1;
        const char* Ab = (const char*)Al[bc];
        const char* Bb = (const char*)Bl[bc];
        const bool more = (kt + 1) < 16;

        // ===== phase 0: quad (mq=0, nq=0) =====
        if (more) {
            stA(kt + 1, bn2, 0);
            asm volatile("s_waitcnt vmcnt(2)" ::: "memory");
        } else {
            asm volatile("s_waitcnt vmcnt(0)" ::: "memory");
        }
        __builtin_amdgcn_sched_barrier(0);
        __builtin_amdgcn_s_barrier();   // tile kt staged by ALL waves
#pragma unroll
        for (int i = 0; i < 4; ++i)
#pragma unroll
            for (int ks = 0; ks < 2; ++ks) {
                int ra = wm + i * 16 + (lane & 15);
                afq[i][ks] = *(const bf16x8*)(Ab + ra * 128 +
                                              ((ks * 64 + kg16) ^ swl));
            }
#pragma unroll
        for (int j = 0; j < 2; ++j)
#pragma unroll
            for (int ks = 0; ks < 2; ++ks) {
                int rb = wn + j * 16 + (lane & 15);
                bq0[j][ks] = *(const bf16x8*)(Bb + rb * 128 +
                                              ((ks * 64 + kg16) ^ swl));
            }
        __builtin_amdgcn_s_barrier();
        asm volatile("s_waitcnt lgkmcnt(0)" ::: "memory");
        __builtin_amdgcn_sched_barrier(0);
        __builtin_amdgcn_s_setprio(1);
#pragma unroll
        for (int ks = 0; ks < 2; ++ks)
#pragma unroll
            for (int i = 0; i < 4; ++i)
#pragma unroll
                for (int j = 0; j < 2; ++j)
                    acc[i][j] = __builtin_amdgcn_mfma_f32_16x16x32_bf16(
                        afq[i][ks], bq0[j][ks], acc[i][j], 0, 0, 0);
        __builtin_amdgcn_s_setprio(0);
        __builtin_amdgcn_s_barrier();

        // ===== phase 1: quad (mq=0, nq=1) =====
        if (more) stA(kt + 1, bn2, 1);
#pragma unroll
        for (int j = 0; j < 2; ++j)
#pragma unroll
            for (int ks = 0; ks < 2; ++ks) {
                int rb = wn + 32 + j * 16 + (lane & 15);
                bq1[j][ks] = *(const bf16x8*)(Bb + rb * 128 +
                                              ((ks * 64 + kg16) ^ swl));
            }
        __builtin_amdgcn_s_barrier();
        asm volatile("s_waitcnt lgkmcnt(0)" ::: "memory");
        __builtin_amdgcn_sched_barrier(0);
        __builtin_amdgcn_s_setprio(1);
#pragma unroll
        for (int ks = 0; ks < 2; ++ks)
#pragma unroll
            for (int i = 0; i < 4; ++i)
#pragma unroll
                for (int j = 0; j < 2; ++j)
                    acc[i][2 + j] = __builtin_amdgcn_mfma_f32_16x16x32_bf16(
                        afq[i][ks], bq1[j][ks], acc[i][2 + j], 0, 0, 0);
        __builtin_amdgcn_s_setprio(0);
        __builtin_amdgcn_s_barrier();

        // ===== phase 2: quad (mq=1, nq=1) =====
        if (more) stB(kt + 1, bn2, 0);
#pragma unroll
        for (int i = 0; i < 4; ++i)
#pragma unroll
            for (int ks = 0; ks < 2; ++ks) {
                int ra = wm + 64 + i * 16 + (lane & 15);
                afq[i][ks] = *(const bf16x8*)(Ab + ra * 128 +
                                              ((ks * 64 + kg16) ^ swl));
            }
        __builtin_amdgcn_s_barrier();
        asm volatile("s_waitcnt lgkmcnt(0)" ::: "memory");
        __builtin_amdgcn_sched_barrier(0);
        __builtin_amdgcn_s_setprio(1);
#pragma unroll
        for (int ks = 0; ks < 2; ++ks)
#pragma unroll
            for (int i = 0; i < 4; ++i)
#pragma unroll
                for (int j = 0; j < 2; ++j)
                    acc[4 + i][2 + j] = __builtin_amdgcn_mfma_f32_16x16x32_bf16(
                        afq[i][ks], bq1[j][ks], acc[4 + i][2 + j], 0, 0, 0);
        __builtin_amdgcn_s_setprio(0);
        __builtin_amdgcn_s_barrier();

        // ===== phase 3: quad (mq=1, nq=0) — no new ds_reads =====
        if (more) stB(kt + 1, bn2, 1);
        __builtin_amdgcn_s_barrier();
        __builtin_amdgcn_s_setprio(1);
#pragma unroll
        for (int ks = 0; ks < 2; ++ks)
#pragma unroll
            for (int i = 0; i < 4; ++i)
#pragma unroll
                for (int j = 0; j < 2; ++j)
                    acc[4 + i][j] = __builtin_amdgcn_mfma_f32_16x16x32_bf16(
                        afq[i][ks], bq0[j][ks], acc[4 + i][j], 0, 0, 0);
        __builtin_amdgcn_s_setprio(0);
        __builtin_amdgcn_s_barrier();
    }

    float bj[4];
#pragma unroll
    for (int j = 0; j < 4; ++j) bj[j] = bias[n0 + wn + j * 16 + (lane & 15)];

    if (hm == 2) {
        // V-transpose epilogue: [bh][d][s], 4 s-rows per lane -> ushort4
#pragma unroll
        for (int i = 0; i < 8; ++i) {
            int row0 = m0 + wm + i * 16 + (g4 << 2);
            int bb = row0 >> 11, ss0 = row0 & 2047;
#pragma unroll
            for (int j = 0; j < 4; ++j) {
                int col = n0 + wn + j * 16 + (lane & 15);
                int hh = col >> 6, dd = col & 63;
                ushort4 o;
                o.x = bfbits(acc[i][j][0] + bj[j]);
                o.y = bfbits(acc[i][j][1] + bj[j]);
                o.z = bfbits(acc[i][j][2] + bj[j]);
                o.w = bfbits(acc[i][j][3] + bj[j]);
                *(ushort4*)((unsigned short*)g.C[z] +
                            (((size_t)(bb * 16 + hh) * 64 + dd) * 2048 + ss0)) = o;
            }
        }
        return;
    }

#pragma unroll
    for (int i = 0; i < 8; ++i)
#pragma unroll
        for (int r = 0; r < 4; ++r) {
            int row = m0 + wm + i * 16 + g4 * 4 + r;
#pragma unroll
            for (int j = 0; j < 4; ++j) {
                int col = n0 + wn + j * 16 + (lane & 15);
                float v = (acc[i][j][r] + bj[j]) * scale;
                if (hm) {
                    int bb = row >> 11, ss = row & 2047;
                    int hh = col >> 6, dd = col & 63;
                    ((unsigned short*)g.C[z])
                        [(((size_t)(bb * 16 + hh) * 2048) + ss) * 64 + dd] =
                        bfbits(v);
                } else {
                    ((unsigned short*)g.C[z])[(size_t)row * 1024 + col] =
                        bfbits(v);
                }
            }
        }
}

// ----------------------------------------------------------- attention ----
// (round-3 proven kernel, verbatim) Qh/Kh: [bh][s][64] bf16 (Q pre-scaled
// by log2(e)/8). VtT: [bh][d][s] bf16. Block = 128 q x (b,h); 4 waves.
// K/V double-buffered LDS via global_load_lds + source XOR swizzle.
__global__ __launch_bounds__(256) void attn_fwd(
    const unsigned short* __restrict__ Qh,
    const unsigned short* __restrict__ Kh,
    const unsigned short* __restrict__ VtT,
    const int* __restrict__ mask,
    unsigned short* __restrict__ Ctx) {
    __shared__ unsigned short KlA[4096], KlB[4096];
    __shared__ unsigned short VlA[4096], VlB[4096];
    __shared__ unsigned short Plds[4][2048];
    __shared__ int cfl[4];

    const int wg = blockIdx.x + (int)gridDim.x * blockIdx.y;
    const int swzid = (wg & 7) * 64 + (wg >> 3);
    const int qt = swzid & 15, bh = swzid >> 4;
    const int b = bh >> 4, h = bh & 15;

    const int t = threadIdx.x, w = t >> 6, lane = t & 63;
    const int wq0 = w * 32;
    const int g = lane >> 4;
    const int kg16 = g * 16;
    const int swl = (lane & 7) << 4;

    const int* mbase = mask + b * SEQ;
    int myclean = 1;
#pragma unroll
    for (int i = 0; i < 2; ++i) {
        int4 m4 = ((const int4*)mbase)[t + i * 256];
        myclean &= (m4.x != 0) & (m4.y != 0) & (m4.z != 0) & (m4.w != 0);
    }
    int wc = __all(myclean);
    if (lane == 0) cfl[w] = wc;

    const char* Qbase = (const char*)Qh + (size_t)bh * 2048 * 128;
    bf16x8 qf[2][2];
#pragma unroll
    for (int nf = 0; nf < 2; ++nf)
#pragma unroll
        for (int ks = 0; ks < 2; ++ks) {
            int row = qt * 128 + wq0 + nf * 16 + (lane & 15);
            qf[nf][ks] = *(const bf16x8*)(Qbase + (size_t)row * 128 +
                                          ks * 64 + kg16);
        }

    bf16x8 onesf;
#pragma unroll
    for (int j = 0; j < 8; ++j) onesf[j] = (__bf16)1.0f;

    f32x4 cacc[2][4], lacc[2];
#pragma unroll
    for (int i = 0; i < 2; ++i) {
        lacc[i] = (f32x4){0.f, 0.f, 0.f, 0.f};
#pragma unroll
        for (int j = 0; j < 4; ++j) cacc[i][j] = (f32x4){0.f, 0.f, 0.f, 0.f};
    }
    float mstate[2] = {-3e38f, -3e38f};

    const char* Kbyte = (const char*)Kh + (size_t)bh * 2048 * 128;
    const char* Vbyte = (const char*)VtT + (size_t)bh * 64 * 4096;

    const int srow = t >> 3;
    const int csw = ((t & 7) * 16) ^ ((srow & 7) << 4);
    const size_t srow128 = (size_t)srow * 128;
    const size_t srow4096 = (size_t)srow * 4096;

    auto stage = [&](unsigned short* Kd, unsigned short* Vd, int kv0) {
        const char* ks = Kbyte + (size_t)kv0 * 128;
        gld_lds16(ks + srow128 + csw,               Kd + w * 512);
        gld_lds16(ks + srow128 + 32 * 128 + csw,    Kd + 2048 + w * 512);
        const char* vs = Vbyte + (size_t)kv0 * 2;
        gld_lds16(vs + srow4096 + csw,              Vd + w * 512);
        gld_lds16(vs + srow4096 + 32 * 4096 + csw,  Vd + 2048 + w * 512);
    };

    __syncthreads();
    const int clean = cfl[0] & cfl[1] & cfl[2] & cfl[3];

    unsigned short* Pw = &Plds[w][0];

    auto compute = [&](const unsigned short* Kl, const unsigned short* Vl,
                       int kv0) {
        f32x4 sacc[4][2];
#pragma unroll
        for (int i = 0; i < 4; ++i)
#pragma unroll
            for (int j = 0; j < 2; ++j) sacc[i][j] = (f32x4){0.f, 0.f, 0.f, 0.f};
#pragma unroll
        for (int ks = 0; ks < 2; ++ks) {
            bf16x8 kf[4];
#pragma unroll
            for (int mf = 0; mf < 4; ++mf) {
                int r = mf * 16 + (lane & 15);
                kf[mf] = *(const bf16x8*)((const char*)Kl + r * 128 +
                                          ((ks * 64 + kg16) ^ swl));
            }
            __builtin_amdgcn_s_setprio(1);
#pragma unroll
            for (int mf = 0; mf < 4; ++mf)
#pragma unroll
                for (int nf = 0; nf < 2; ++nf)
                    sacc[mf][nf] = __builtin_amdgcn_mfma_f32_16x16x32_bf16(
                        kf[mf], qf[nf][ks], sacc[mf][nf], 0, 0, 0);
            __builtin_amdgcn_s_setprio(0);
        }

        if (!clean) {
#pragma unroll
            for (int mf = 0; mf < 4; ++mf) {
                int4 mk = *(const int4*)(mbase + kv0 + mf * 16 + g * 4);
#pragma unroll
                for (int r = 0; r < 4; ++r) {
                    if ((&mk.x)[r] == 0) {
                        sacc[mf][0][r] = -1e9f;
                        sacc[mf][1][r] = -1e9f;
                    }
                }
            }
        }

        float vm[2];
#pragma unroll
        for (int nf = 0; nf < 2; ++nf) {
            float a0 = fmaxf(fmaxf(sacc[0][nf][0], sacc[0][nf][1]),
                             fmaxf(sacc[0][nf][2], sacc[0][nf][3]));
            float a1 = fmaxf(fmaxf(sacc[1][nf][0], sacc[1][nf][1]),
                             fmaxf(sacc[1][nf][2], sacc[1][nf][3]));
            float a2 = fmaxf(fmaxf(sacc[2][nf][0], sacc[2][nf][1]),
                             fmaxf(sacc[2][nf][2], sacc[2][nf][3]));
            float a3 = fmaxf(fmaxf(sacc[3][nf][0], sacc[3][nf][1]),
                             fmaxf(sacc[3][nf][2], sacc[3][nf][3]));
            float m4x = fmaxf(fmaxf(a0, a1), fmaxf(a2, a3));
            m4x = fmaxf(m4x, __shfl_xor(m4x, 16));
            vm[nf] = fmaxf(m4x, __shfl_xor(m4x, 32));
        }
        if (!__all((vm[0] <= mstate[0] + 8.f) & (vm[1] <= mstate[1] + 8.f))) {
            float sc[2];
#pragma unroll
            for (int nf = 0; nf < 2; ++nf) {
                float mnew = fmaxf(mstate[nf], vm[nf]);
                sc[nf] = EXP2F(mstate[nf] - mnew);
                mstate[nf] = mnew;
            }
#pragma unroll
            for (int mq = 0; mq < 2; ++mq)
#pragma unroll
                for (int r = 0; r < 4; ++r) {
                    float scb = __shfl(sc[mq], g * 4 + r);
                    lacc[mq][r] *= scb;
#pragma unroll
                    for (int nd = 0; nd < 4; ++nd) cacc[mq][nd][r] *= scb;
                }
        }

#pragma unroll
        for (int nf = 0; nf < 2; ++nf) {
            float mn = mstate[nf];
#pragma unroll
            for (int mf = 0; mf < 4; ++mf) {
                unsigned int d0 = pk2bf(EXP2F(sacc[mf][nf][0] - mn),
                                        EXP2F(sacc[mf][nf][1] - mn));
                unsigned int d1 = pk2bf(EXP2F(sacc[mf][nf][2] - mn),
                                        EXP2F(sacc[mf][nf][3] - mn));
                int q = nf * 16 + (lane & 15);
                int kb = mf * 32 + g * 8;
                unsigned long long pv =
                    (unsigned long long)d0 | ((unsigned long long)d1 << 32);
                *(unsigned long long*)((char*)Pw + q * 128 +
                                       (kb ^ ((q & 7) << 4))) = pv;
            }
        }

#pragma unroll
        for (int ks = 0; ks < 2; ++ks) {
            bf16x8 pa[2], vf[4];
#pragma unroll
            for (int mq = 0; mq < 2; ++mq) {
                int r = mq * 16 + (lane & 15);
                pa[mq] = *(const bf16x8*)((const char*)Pw + r * 128 +
                                          ((ks * 64 + kg16) ^ swl));
            }
#pragma unroll
            for (int nd = 0; nd < 4; ++nd) {
                int r = nd * 16 + (lane & 15);
                vf[nd] = *(const bf16x8*)((const char*)Vl + r * 128 +
                                          ((ks * 64 + kg16) ^ swl));
            }
            __builtin_amdgcn_s_setprio(1);
#pragma unroll
            for (int mq = 0; mq < 2; ++mq) {
                lacc[mq] = __builtin_amdgcn_mfma_f32_16x16x32_bf16(
                    pa[mq], onesf, lacc[mq], 0, 0, 0);
#pragma unroll
                for (int nd = 0; nd < 4; ++nd)
                    cacc[mq][nd] = __builtin_amdgcn_mfma_f32_16x16x32_bf16(
                        pa[mq], vf[nd], cacc[mq][nd], 0, 0, 0);
            }
            __builtin_amdgcn_s_setprio(0);
        }
    };

    stage(KlA, VlA, 0);
    __syncthreads();
    for (int i = 0; i < 16; ++i) {
        const int kv0 = i * 128;
        if (kv0 + 64 < SEQ) stage(KlB, VlB, kv0 + 64);
        compute(KlA, VlA, kv0);
        __syncthreads();
        if (kv0 + 128 < SEQ) stage(KlA, VlA, kv0 + 128);
        compute(KlB, VlB, kv0 + 64);
        __syncthreads();
    }

#pragma unroll
    for (int mq = 0; mq < 2; ++mq)
#pragma unroll
        for (int r = 0; r < 4; ++r) {
            float inv = RCPF(lacc[mq][r]);
            size_t row = (size_t)b * SEQ + qt * 128 + wq0 + mq * 16 +
                         g * 4 + r;
#pragma unroll
            for (int nd = 0; nd < 4; ++nd) {
                int col = h * 64 + nd * 16 + (lane & 15);
                Ctx[row * 1024 + col] = bfbits(cacc[mq][nd][r] * inv);
            }
        }
}

// -------------------------------------------------------------- launch ----
extern "C" void kernel_launch(void* const* d_in, const int* in_sizes, int n_in,
                              void* d_out, int out_size, void* d_ws, size_t ws_size,
                              hipStream_t stream) {
    const float* q   = (const float*)d_in[0];
    const float* k   = (const float*)d_in[1];
    const float* v   = (const float*)d_in[2];
    const int* mask  = (const int*)d_in[3];
    const float* Wq  = (const float*)d_in[4];
    const float* bq  = (const float*)d_in[5];
    const float* Wk  = (const float*)d_in[6];
    const float* bk  = (const float*)d_in[7];
    const float* Wv  = (const float*)d_in[8];
    const float* bv  = (const float*)d_in[9];
    const float* Wo  = (const float*)d_in[10];
    const float* bo  = (const float*)d_in[11];

    unsigned short* ws = (unsigned short*)d_ws;
    const size_t NX = (size_t)MROWS * D_MODEL;   // 4194304 elems
    const size_t NW = (size_t)D_MODEL * D_MODEL; // 1048576 elems
    unsigned short* Xq  = ws;
    unsigned short* Xk  = Xq + NX;
    unsigned short* Xv  = Xk + NX;
    unsigned short* Wqb = Xv + NX;
    unsigned short* Wkb = Wqb + NW;
    unsigned short* Wvb = Wkb + NW;
    unsigned short* Wob = Wvb + NW;
    unsigned short* Qhd = Wob + NW;
    unsigned short* Khd = Qhd + NX;
    unsigned short* Vtt = Khd + NX;
    unsigned short* Cx  = Vtt + NX;

    PrepArgs pa;
    pa.src[0] = q;  pa.src[1] = k;  pa.src[2] = v;
    pa.src[3] = Wq; pa.src[4] = Wk; pa.src[5] = Wv; pa.src[6] = Wo;
    pa.dst[0] = Xq;  pa.dst[1] = Xk;  pa.dst[2] = Xv;
    pa.dst[3] = Wqb; pa.dst[4] = Wkb; pa.dst[5] = Wvb; pa.dst[6] = Wob;
    for (int i = 0; i < 3; ++i) pa.n4[i] = (int)(NX / 4);
    for (int i = 3; i < 7; ++i) pa.n4[i] = (int)(NW / 4);
    prep_cvt<<<dim3(256, 7), dim3(256), 0, stream>>>(pa);

    GemmArgs gq;
    gq.A[0] = Xq;  gq.A[1] = Xk;  gq.A[2] = Xv;
    gq.W[0] = Wqb; gq.W[1] = Wkb; gq.W[2] = Wvb;
    gq.bias[0] = bq; gq.bias[1] = bk; gq.bias[2] = bv;
    gq.C[0] = Qhd; gq.C[1] = Khd; gq.C[2] = Vtt;
    gq.scale[0] = 0.125f * 1.44269504088896340736f;   // 1/sqrt(64) * log2(e)
    gq.scale[1] = 1.f; gq.scale[2] = 1.f;
    gq.hm[0] = 1; gq.hm[1] = 1; gq.hm[2] = 2;
    gemm_8p<<<dim3(16, 4, 3), dim3(512), 0, stream>>>(gq);

    attn_fwd<<<dim3(16, 32), dim3(256), 0, stream>>>(Qhd, Khd, Vtt, mask, Cx);

    GemmArgs go;
    go.A[0] = Cx; go.W[0] = Wob; go.bias[0] = bo; go.C[0] = d_out;
    go.scale[0] = 1.f; go.hm[0] = 0;
    go.A[1] = go.A[2] = nullptr; go.W[1] = go.W[2] = nullptr;
    go.bias[1] = go.bias[2] = nullptr; go.C[1] = go.C[2] = nullptr;
    go.scale[1] = go.scale[2] = 1.f; go.hm[1] = go.hm[2] = 0;
    gemm_bt<true, 128, 64><<<dim3(32, 16, 1), dim3(256), 0, stream>>>(go);
}

// Round 7
// 234.521 us; speedup vs baseline: 1.4208x; 1.0414x over previous
//
#include <hip/hip_runtime.h>
#include <stdint.h>

#define D_MODEL 1024
#define NH 16
#define DK 64
#define BATCH 2
#define SEQ 2048
#define MROWS (BATCH*SEQ)   // 4096

typedef float f32x4 __attribute__((ext_vector_type(4)));
typedef float f32x16 __attribute__((ext_vector_type(16)));
typedef __bf16 bf16x8 __attribute__((ext_vector_type(8)));

#define AS1 __attribute__((address_space(1)))
#define AS3 __attribute__((address_space(3)))

#if __has_builtin(__builtin_amdgcn_exp2f)
#define EXP2F(x) __builtin_amdgcn_exp2f(x)
#else
#define EXP2F(x) exp2f(x)
#endif
#if __has_builtin(__builtin_amdgcn_rcpf)
#define RCPF(x) __builtin_amdgcn_rcpf(x)
#else
#define RCPF(x) (1.0f/(x))
#endif

// exchange: a' = {a.lo, b.lo}, b' = {a.hi, b.hi}  (v_permlane32_swap_b32)
#define PERMSWAP(a, b) \
    asm volatile("s_nop 1\n\tv_permlane32_swap_b32 %0, %1" \
                 : "+v"(a), "+v"(b))

// async global->LDS, 16B per lane, dest = wave-uniform base + lane*16
static __device__ __forceinline__ void gld_lds16(const void* g, void* l) {
    __builtin_amdgcn_global_load_lds((const AS1 unsigned int*)g,
                                     (AS3 unsigned int*)l, 16, 0, 0);
}

// HW f32->bf16 (RNE); compiler pairs adjacent casts into v_cvt_pk_bf16_f32
static __device__ __forceinline__ unsigned short bfbits(float f) {
    return __builtin_bit_cast(unsigned short, (__bf16)f);
}
static __device__ __forceinline__ unsigned int pk2bf(float a, float b) {
    return (unsigned int)bfbits(a) | ((unsigned int)bfbits(b) << 16);
}

static __device__ __forceinline__ float vmax16(const f32x16& v) {
    float a = fmaxf(fmaxf(v[0], v[1]), fmaxf(v[2], v[3]));
    float b = fmaxf(fmaxf(v[4], v[5]), fmaxf(v[6], v[7]));
    float c = fmaxf(fmaxf(v[8], v[9]), fmaxf(v[10], v[11]));
    float d = fmaxf(fmaxf(v[12], v[13]), fmaxf(v[14], v[15]));
    return fmaxf(fmaxf(a, b), fmaxf(c, d));
}

// ---------------------------------------------------------------- prep ----
struct PrepArgs {
    const float* src[7];
    unsigned short* dst[7];
    int n4[7];
};

__global__ __launch_bounds__(256) void prep_cvt(PrepArgs a) {
    const int z = blockIdx.y;
    const float4* s = (const float4*)a.src[z];
    uint2* d = (uint2*)a.dst[z];
    const int n = a.n4[z];
    for (int i = blockIdx.x * blockDim.x + threadIdx.x; i < n;
         i += gridDim.x * blockDim.x) {
        float4 v = s[i];
        uint2 o;
        o.x = pk2bf(v.x, v.y);
        o.y = pk2bf(v.z, v.w);
        d[i] = o;
    }
}

// ---------------------------------------------------------------- GEMM ----
// C[m,n] = (sum_k A[m,k]*W[n,k] + bias[n]) * scale ; K=1024, BK=64, 4 waves.
// hm: 0 flat [row][1024]; 1 head-major [bh][s][64]; 2 V-transposed [bh][d][s].
struct GemmArgs {
    const unsigned short* A[3];
    const unsigned short* W[3];
    const float* bias[3];
    void* C[3];
    float scale[3];
    int hm[3];
};

template<bool OUT_F32, int BM, int BN>
__global__ __launch_bounds__(256) void gemm_bt(GemmArgs g) {
    constexpr int IM = BM / 32;
    constexpr int JN = BN / 32;
    __shared__ unsigned short As[BM * 64];
    __shared__ unsigned short Bs[BN * 64];
    const int z = blockIdx.z;
    const char* A = (const char*)g.A[z];
    const char* W = (const char*)g.W[z];
    const float* bias = g.bias[z];
    const float scale = g.scale[z];
    const int hm = g.hm[z];
    const int t = threadIdx.x;
    const int w = t >> 6, lane = t & 63;
    const int m0 = blockIdx.x * BM, n0 = blockIdx.y * BN;
    const int wm = (w >> 1) * (BM / 2), wn = (w & 1) * (BN / 2);

    const int srow = t >> 3;
    const int csw = ((t & 7) * 16) ^ ((srow & 7) << 4);
    const char* pA = A + (size_t)(m0 + srow) * 2048 + csw;
    const char* pW = W + (size_t)(n0 + srow) * 2048 + csw;

    f32x4 acc[IM][JN];
#pragma unroll
    for (int i = 0; i < IM; ++i)
#pragma unroll
        for (int j = 0; j < JN; ++j)
            acc[i][j] = (f32x4){0.f, 0.f, 0.f, 0.f};

    const int g4 = lane >> 4;
    const int kg16 = g4 * 16;
    const int swl = (lane & 7) << 4;

    for (int kt = 0; kt < 16; ++kt) {
        __syncthreads();
#pragma unroll
        for (int p = 0; p < IM; ++p)
            gld_lds16(pA + (size_t)p * (32 * 2048), &As[w * 512 + p * 2048]);
#pragma unroll
        for (int p = 0; p < JN; ++p)
            gld_lds16(pW + (size_t)p * (32 * 2048), &Bs[w * 512 + p * 2048]);
        pA += 128; pW += 128;
        __syncthreads();
#pragma unroll
        for (int ks = 0; ks < 2; ++ks) {
            bf16x8 af[IM], bfv[JN];
#pragma unroll
            for (int i = 0; i < IM; ++i) {
                int ra = wm + i * 16 + (lane & 15);
                af[i] = *(const bf16x8*)((const char*)As + ra * 128 +
                                         ((ks * 64 + kg16) ^ swl));
            }
#pragma unroll
            for (int j = 0; j < JN; ++j) {
                int rb = wn + j * 16 + (lane & 15);
                bfv[j] = *(const bf16x8*)((const char*)Bs + rb * 128 +
                                          ((ks * 64 + kg16) ^ swl));
            }
            __builtin_amdgcn_s_setprio(1);
#pragma unroll
            for (int i = 0; i < IM; ++i)
#pragma unroll
                for (int j = 0; j < JN; ++j)
                    acc[i][j] = __builtin_amdgcn_mfma_f32_16x16x32_bf16(
                        af[i], bfv[j], acc[i][j], 0, 0, 0);
            __builtin_amdgcn_s_setprio(0);
        }
    }

    float bj[JN];
#pragma unroll
    for (int j = 0; j < JN; ++j) bj[j] = bias[n0 + wn + j * 16 + (lane & 15)];

    if (hm == 2) {
        // V-transpose epilogue: [bh][d][s], 4 s-rows per lane -> ushort4
#pragma unroll
        for (int i = 0; i < IM; ++i) {
            int row0 = m0 + wm + i * 16 + (g4 << 2);
            int bb = row0 >> 11, ss0 = row0 & 2047;
#pragma unroll
            for (int j = 0; j < JN; ++j) {
                int col = n0 + wn + j * 16 + (lane & 15);
                int hh = col >> 6, dd = col & 63;
                ushort4 o;
                o.x = bfbits(acc[i][j][0] + bj[j]);
                o.y = bfbits(acc[i][j][1] + bj[j]);
                o.z = bfbits(acc[i][j][2] + bj[j]);
                o.w = bfbits(acc[i][j][3] + bj[j]);
                *(ushort4*)((unsigned short*)g.C[z] +
                            (((size_t)(bb * 16 + hh) * 64 + dd) * 2048 + ss0)) = o;
            }
        }
        return;
    }

#pragma unroll
    for (int i = 0; i < IM; ++i)
#pragma unroll
        for (int r = 0; r < 4; ++r) {
            int row = m0 + wm + i * 16 + g4 * 4 + r;
#pragma unroll
            for (int j = 0; j < JN; ++j) {
                int col = n0 + wn + j * 16 + (lane & 15);
                float v = (acc[i][j][r] + bj[j]) * scale;
                if (OUT_F32) {
                    ((float*)g.C[z])[(size_t)row * 1024 + col] = v;
                } else if (hm) {
                    int bb = row >> 11, ss = row & 2047;
                    int hh = col >> 6, dd = col & 63;
                    ((unsigned short*)g.C[z])
                        [(((size_t)(bb * 16 + hh) * 2048) + ss) * 64 + dd] =
                        bfbits(v);
                } else {
                    ((unsigned short*)g.C[z])[(size_t)row * 1024 + col] =
                        bfbits(v);
                }
            }
        }
}

// ----------------------------------------------------------- attention ----
// 32x32-MFMA flash attention, swapped QK^T, P fully in-register.
// Qh/Kh: [bh][s][64] bf16 (Q pre-scaled by log2(e)/8). VtT: [bh][d][s] bf16.
// Block = 128 q x (b,h); 4 waves x 32 q. K/V double-buffered LDS via
// global_load_lds + source XOR swizzle (identical staging to round 3).
// S^T = mfma_32x32x16(K, Q): lane holds q=lane&31, 32 key-values in regs
// (key = kb*32 + (r&3)+8*(r>>2)+4*hi). Softmax in-lane + 1 shfl_xor(32).
// PV A-frags rebuilt with cvt_pk + v_permlane32_swap_b32 (no P LDS bounce).
__global__ __launch_bounds__(256) void attn_fwd(
    const unsigned short* __restrict__ Qh,
    const unsigned short* __restrict__ Kh,
    const unsigned short* __restrict__ VtT,
    const int* __restrict__ mask,
    unsigned short* __restrict__ Ctx) {
    __shared__ unsigned short KlA[4096], KlB[4096];
    __shared__ unsigned short VlA[4096], VlB[4096];
    __shared__ int cfl[4];

    const int wg = blockIdx.x + (int)gridDim.x * blockIdx.y;
    const int swzid = (wg & 7) * 64 + (wg >> 3);
    const int qt = swzid & 15, bh = swzid >> 4;
    const int b = bh >> 4, h = bh & 15;

    const int t = threadIdx.x, w = t >> 6, lane = t & 63;
    const int hi = lane >> 5, q5 = lane & 31;
    const int swl5 = (q5 & 7) << 4;

    // block-wide mask-clean check
    const int* mbase = mask + b * SEQ;
    int myclean = 1;
#pragma unroll
    for (int i = 0; i < 2; ++i) {
        int4 m4 = ((const int4*)mbase)[t + i * 256];
        myclean &= (m4.x != 0) & (m4.y != 0) & (m4.z != 0) & (m4.w != 0);
    }
    int wc = __all(myclean);
    if (lane == 0) cfl[w] = wc;

    // hoist Q fragments: B-frag B[k=d][n=q]: lane needs q=lane&31,
    // d = t4*16 + hi*8 + j  -> 4 x 16B chunks of the 128B Q row
    const char* Qbase = (const char*)Qh + (size_t)bh * 2048 * 128;
    const int qrow = qt * 128 + w * 32 + q5;
    bf16x8 qf[4];
#pragma unroll
    for (int t4 = 0; t4 < 4; ++t4)
        qf[t4] = *(const bf16x8*)(Qbase + (size_t)qrow * 128 +
                                  t4 * 32 + hi * 16);

    f32x16 cacc[2];
#pragma unroll
    for (int r = 0; r < 16; ++r) { cacc[0][r] = 0.f; cacc[1][r] = 0.f; }
    float mstate = -3e38f, lstate = 0.f;

    const char* Kbyte = (const char*)Kh + (size_t)bh * 2048 * 128;
    const char* Vbyte = (const char*)VtT + (size_t)bh * 64 * 4096;

    const int srow = t >> 3;
    const int csw = ((t & 7) * 16) ^ ((srow & 7) << 4);
    const size_t srow128 = (size_t)srow * 128;
    const size_t srow4096 = (size_t)srow * 4096;

    auto stage = [&](unsigned short* Kd, unsigned short* Vd, int kv0) {
        const char* ks = Kbyte + (size_t)kv0 * 128;
        gld_lds16(ks + srow128 + csw,               Kd + w * 512);
        gld_lds16(ks + srow128 + 32 * 128 + csw,    Kd + 2048 + w * 512);
        const char* vs = Vbyte + (size_t)kv0 * 2;
        gld_lds16(vs + srow4096 + csw,              Vd + w * 512);
        gld_lds16(vs + srow4096 + 32 * 4096 + csw,  Vd + 2048 + w * 512);
    };

    __syncthreads();   // cfl ready (covered by first stage sync below too)
    const int clean = cfl[0] & cfl[1] & cfl[2] & cfl[3];

    auto compute = [&](const unsigned short* Kl, const unsigned short* Vl,
                       int kv0) {
        // S^T = K . Q^T : A-frag = K[key][d] from LDS, B-frag = qf regs
        f32x16 sacc[2];
#pragma unroll
        for (int r = 0; r < 16; ++r) { sacc[0][r] = 0.f; sacc[1][r] = 0.f; }
#pragma unroll
        for (int t4 = 0; t4 < 4; ++t4) {
            int off = (t4 * 32 + hi * 16) ^ swl5;
            bf16x8 kf0 = *(const bf16x8*)((const char*)Kl + q5 * 128 + off);
            bf16x8 kf1 = *(const bf16x8*)((const char*)Kl + (32 + q5) * 128 + off);
            __builtin_amdgcn_s_setprio(1);
            sacc[0] = __builtin_amdgcn_mfma_f32_32x32x16_bf16(
                kf0, qf[t4], sacc[0], 0, 0, 0);
            sacc[1] = __builtin_amdgcn_mfma_f32_32x32x16_bf16(
                kf1, qf[t4], sacc[1], 0, 0, 0);
            __builtin_amdgcn_s_setprio(0);
        }

        if (!clean) {
#pragma unroll
            for (int kb = 0; kb < 2; ++kb)
#pragma unroll
                for (int r = 0; r < 16; ++r) {
                    int key = kb * 32 + (r & 3) + 8 * (r >> 2) + 4 * hi;
                    if (mbase[kv0 + key] == 0) sacc[kb][r] = -1e9f;
                }
        }

        // per-q max: in-lane tree + partner half via xor-32
        float vm = fmaxf(vmax16(sacc[0]), vmax16(sacc[1]));
        vm = fmaxf(vm, __shfl_xor(vm, 32));

        // defer-max rescale (THR=8, log2 domain)
        if (!__all(vm <= mstate + 8.f)) {
            float mnew = fmaxf(mstate, vm);
            float sc = EXP2F(mstate - mnew);
            mstate = mnew;
            lstate *= sc;
#pragma unroll
            for (int r = 0; r < 16; ++r) {
                float scb = __shfl(sc, (r & 3) + 8 * (r >> 2) + 4 * hi);
                cacc[0][r] *= scb;
                cacc[1][r] *= scb;
            }
        }

        // P = 2^(S'-m): exp + pack in-register; row-sum in-lane
        const float mn = mstate;
        float ssum = 0.f;
        unsigned int Ap[2][4], Bp[2][4];
#pragma unroll
        for (int kb = 0; kb < 2; ++kb)
#pragma unroll
            for (int si = 0; si < 4; ++si) {
                float e0 = EXP2F(sacc[kb][4 * si + 0] - mn);
                float e1 = EXP2F(sacc[kb][4 * si + 1] - mn);
                float e2 = EXP2F(sacc[kb][4 * si + 2] - mn);
                float e3 = EXP2F(sacc[kb][4 * si + 3] - mn);
                ssum += (e0 + e1) + (e2 + e3);
                Ap[kb][si] = pk2bf(e0, e1);
                Bp[kb][si] = pk2bf(e2, e3);
            }
        ssum += __shfl_xor(ssum, 32);
        lstate += ssum;

        // PV: A-frag per 16-key chunk via 2 permlane swaps; B-frag from Vt
#pragma unroll
        for (int ct = 0; ct < 4; ++ct) {
            const int kb = ct >> 1, sA = (ct & 1) * 2;
            unsigned int w0 = Ap[kb][sA], w2 = Ap[kb][sA + 1];
            unsigned int w1 = Bp[kb][sA], w3 = Bp[kb][sA + 1];
            PERMSWAP(w0, w2);   // w0 = keys(+0,+1) elems; w2 = keys(+4,+5)
            PERMSWAP(w1, w3);   // w1 = keys(+2,+3);      w3 = keys(+6,+7)
            union { unsigned int u[4]; bf16x8 v; } pa;
            pa.u[0] = w0; pa.u[1] = w1; pa.u[2] = w2; pa.u[3] = w3;

            int off = (ct * 32 + hi * 16) ^ swl5;
            bf16x8 vf0 = *(const bf16x8*)((const char*)Vl + q5 * 128 + off);
            bf16x8 vf1 = *(const bf16x8*)((const char*)Vl + (32 + q5) * 128 + off);
            __builtin_amdgcn_s_setprio(1);
            cacc[0] = __builtin_amdgcn_mfma_f32_32x32x16_bf16(
                pa.v, vf0, cacc[0], 0, 0, 0);
            cacc[1] = __builtin_amdgcn_mfma_f32_32x32x16_bf16(
                pa.v, vf1, cacc[1], 0, 0, 0);
            __builtin_amdgcn_s_setprio(0);
        }
    };

    // 2-phase pipeline, statically double-unrolled (A/B buffers)
    stage(KlA, VlA, 0);
    __syncthreads();
    for (int i = 0; i < 16; ++i) {
        const int kv0 = i * 128;
        if (kv0 + 64 < SEQ) stage(KlB, VlB, kv0 + 64);
        compute(KlA, VlA, kv0);
        __syncthreads();
        if (kv0 + 128 < SEQ) stage(KlA, VlA, kv0 + 128);
        compute(KlB, VlB, kv0 + 64);
        __syncthreads();
    }

    // finalize: 1/l broadcast to C-row layout, store bf16
    const float inv = RCPF(lstate);
#pragma unroll
    for (int r = 0; r < 16; ++r) {
        int cr = (r & 3) + 8 * (r >> 2) + 4 * hi;
        float invr = __shfl(inv, cr);
        size_t row = (size_t)b * SEQ + qt * 128 + w * 32 + cr;
        Ctx[row * 1024 + h * 64 + q5]      = bfbits(cacc[0][r] * invr);
        Ctx[row * 1024 + h * 64 + 32 + q5] = bfbits(cacc[1][r] * invr);
    }
}

// -------------------------------------------------------------- launch ----
extern "C" void kernel_launch(void* const* d_in, const int* in_sizes, int n_in,
                              void* d_out, int out_size, void* d_ws, size_t ws_size,
                              hipStream_t stream) {
    const float* q   = (const float*)d_in[0];
    const float* k   = (const float*)d_in[1];
    const float* v   = (const float*)d_in[2];
    const int* mask  = (const int*)d_in[3];
    const float* Wq  = (const float*)d_in[4];
    const float* bq  = (const float*)d_in[5];
    const float* Wk  = (const float*)d_in[6];
    const float* bk  = (const float*)d_in[7];
    const float* Wv  = (const float*)d_in[8];
    const float* bv  = (const float*)d_in[9];
    const float* Wo  = (const float*)d_in[10];
    const float* bo  = (const float*)d_in[11];

    unsigned short* ws = (unsigned short*)d_ws;
    const size_t NX = (size_t)MROWS * D_MODEL;   // 4194304 elems
    const size_t NW = (size_t)D_MODEL * D_MODEL; // 1048576 elems
    unsigned short* Xq  = ws;
    unsigned short* Xk  = Xq + NX;
    unsigned short* Xv  = Xk + NX;
    unsigned short* Wqb = Xv + NX;
    unsigned short* Wkb = Wqb + NW;
    unsigned short* Wvb = Wkb + NW;
    unsigned short* Wob = Wvb + NW;
    unsigned short* Qhd = Wob + NW;
    unsigned short* Khd = Qhd + NX;
    unsigned short* Vtt = Khd + NX;
    unsigned short* Cx  = Vtt + NX;

    PrepArgs pa;
    pa.src[0] = q;  pa.src[1] = k;  pa.src[2] = v;
    pa.src[3] = Wq; pa.src[4] = Wk; pa.src[5] = Wv; pa.src[6] = Wo;
    pa.dst[0] = Xq;  pa.dst[1] = Xk;  pa.dst[2] = Xv;
    pa.dst[3] = Wqb; pa.dst[4] = Wkb; pa.dst[5] = Wvb; pa.dst[6] = Wob;
    for (int i = 0; i < 3; ++i) pa.n4[i] = (int)(NX / 4);
    for (int i = 3; i < 7; ++i) pa.n4[i] = (int)(NW / 4);
    prep_cvt<<<dim3(256, 7), dim3(256), 0, stream>>>(pa);

    GemmArgs gq;
    gq.A[0] = Xq;  gq.A[1] = Xk;  gq.A[2] = Xv;
    gq.W[0] = Wqb; gq.W[1] = Wkb; gq.W[2] = Wvb;
    gq.bias[0] = bq; gq.bias[1] = bk; gq.bias[2] = bv;
    gq.C[0] = Qhd; gq.C[1] = Khd; gq.C[2] = Vtt;
    gq.scale[0] = 0.125f * 1.44269504088896340736f;   // 1/sqrt(64) * log2(e)
    gq.scale[1] = 1.f; gq.scale[2] = 1.f;
    gq.hm[0] = 1; gq.hm[1] = 1; gq.hm[2] = 2;
    gemm_bt<false, 128, 128><<<dim3(32, 8, 3), dim3(256), 0, stream>>>(gq);

    attn_fwd<<<dim3(16, 32), dim3(256), 0, stream>>>(Qhd, Khd, Vtt, mask, Cx);

    GemmArgs go;
    go.A[0] = Cx; go.W[0] = Wob; go.bias[0] = bo; go.C[0] = d_out;
    go.scale[0] = 1.f; go.hm[0] = 0;
    go.A[1] = go.A[2] = nullptr; go.W[1] = go.W[2] = nullptr;
    go.bias[1] = go.bias[2] = nullptr; go.C[1] = go.C[2] = nullptr;
    go.scale[1] = go.scale[2] = 1.f; go.hm[1] = go.hm[2] = 0;
    gemm_bt<true, 128, 64><<<dim3(32, 16, 1), dim3(256), 0, stream>>>(go);
}